// Round 2
// baseline (396.915 us; speedup 1.0000x reference)
//
#include <hip/hip_runtime.h>
#include <math.h>

// Quantum circuit collapses analytically:
//   z_w = cos(q_params[w]) * cos(features[w])   (RZ layer is pure phase -> no-op on probs)
//   q_out = [z0, z0*z1, z0*z1*z2, z0*z1*z2*z3]  (CNOT chain = parity of independent bits)
// Then MLP 4->64 (relu) -> 4, batchnorm over batch.

__global__ void k_init(float* acc) {
    if (threadIdx.x < 8) acc[threadIdx.x] = 0.0f;
}

__global__ __launch_bounds__(256) void k_main(
    const float* __restrict__ x,
    const float* __restrict__ qp,
    const float* __restrict__ W1,
    const float* __restrict__ b1,
    const float* __restrict__ W2,
    const float* __restrict__ b2,
    float* __restrict__ logits,
    float* __restrict__ acc,
    int B)
{
    __shared__ float sW1[256];   // [j][w], row-major 64x4
    __shared__ float sW2t[256];  // [j][k]  (transpose of W2 4x64)
    __shared__ float sb1[64];
    __shared__ float sred[32];   // 4 waves x 8 partials

    const int tid = threadIdx.x;
    sW1[tid]  = W1[tid];
    sW2t[tid] = W2[(tid & 3) * 64 + (tid >> 2)];
    if (tid < 64) sb1[tid] = b1[tid];
    __syncthreads();

    const int b = blockIdx.x * 256 + tid;
    float l0 = 0.f, l1 = 0.f, l2 = 0.f, l3 = 0.f;

    if (b < B) {
        const float* xb = x + (size_t)b * 1296;  // 36*36, 16B-aligned rows
        float f0 = 0.f, f1 = 0.f, f2 = 0.f, f3 = 0.f;
        #pragma unroll
        for (int r = 0; r < 6; ++r) {
            const float4* row = (const float4*)(xb + r * 36);
            float4 v0 = row[0], v1 = row[1], v2 = row[2];
            float4 v3 = row[3], v4 = row[4], v5 = row[5];
            f0 += v0.x + v0.y + v0.z + v0.w + v1.x + v1.y;  // cols 0..5
            f1 += v1.z + v1.w + v2.x + v2.y + v2.z + v2.w;  // cols 6..11
            f2 += v3.x + v3.y + v3.z + v3.w + v4.x + v4.y;  // cols 12..17
            f3 += v4.z + v4.w + v5.x + v5.y + v5.z + v5.w;  // cols 18..23
        }
        const float inv36 = 1.0f / 36.0f;
        float z0 = cosf(qp[0]) * cosf(f0 * inv36);
        float z1 = cosf(qp[1]) * cosf(f1 * inv36);
        float z2 = cosf(qp[2]) * cosf(f2 * inv36);
        float z3 = cosf(qp[3]) * cosf(f3 * inv36);
        float q0 = z0;
        float q1 = q0 * z1;
        float q2 = q1 * z2;
        float q3 = q2 * z3;

        l0 = b2[0]; l1 = b2[1]; l2 = b2[2]; l3 = b2[3];
        #pragma unroll 8
        for (int j = 0; j < 64; ++j) {
            float h = sb1[j];
            h = fmaf(sW1[4*j+0], q0, h);
            h = fmaf(sW1[4*j+1], q1, h);
            h = fmaf(sW1[4*j+2], q2, h);
            h = fmaxf(fmaf(sW1[4*j+3], q3, h), 0.0f);
            l0 = fmaf(sW2t[4*j+0], h, l0);
            l1 = fmaf(sW2t[4*j+1], h, l1);
            l2 = fmaf(sW2t[4*j+2], h, l2);
            l3 = fmaf(sW2t[4*j+3], h, l3);
        }
        ((float4*)logits)[b] = make_float4(l0, l1, l2, l3);
    }

    // block reduction of sum and sumsq per channel (inactive lanes contribute 0)
    float v[8] = {l0, l1, l2, l3, l0*l0, l1*l1, l2*l2, l3*l3};
    #pragma unroll
    for (int off = 32; off >= 1; off >>= 1) {
        #pragma unroll
        for (int i = 0; i < 8; ++i) v[i] += __shfl_down(v[i], off);
    }
    const int lane = tid & 63, wv = tid >> 6;
    if (lane == 0) {
        #pragma unroll
        for (int i = 0; i < 8; ++i) sred[wv * 8 + i] = v[i];
    }
    __syncthreads();
    if (tid < 8) {
        float s = sred[tid] + sred[tid + 8] + sred[tid + 16] + sred[tid + 24];
        atomicAdd(&acc[tid], s);
    }
}

__global__ __launch_bounds__(256) void k_norm(
    const float* __restrict__ logits,
    const float* __restrict__ acc,
    const float* __restrict__ gamma,
    const float* __restrict__ beta,
    float* __restrict__ out,
    int B, float invB)
{
    __shared__ float sc[4], sh[4];
    if (threadIdx.x < 4) {
        const int k = threadIdx.x;
        float mu   = acc[k] * invB;
        float var  = acc[4 + k] * invB - mu * mu;
        float rstd = 1.0f / sqrtf(var + 1e-5f);
        float g = gamma[k] * rstd;
        sc[k] = g;
        sh[k] = beta[k] - mu * g;
    }
    __syncthreads();
    const int b = blockIdx.x * 256 + threadIdx.x;
    if (b >= B) return;
    float4 l = ((const float4*)logits)[b];
    float4 o;
    o.x = fmaf(sc[0], l.x, sh[0]);
    o.y = fmaf(sc[1], l.y, sh[1]);
    o.z = fmaf(sc[2], l.z, sh[2]);
    o.w = fmaf(sc[3], l.w, sh[3]);
    ((float4*)out)[b] = o;
}

extern "C" void kernel_launch(void* const* d_in, const int* in_sizes, int n_in,
                              void* d_out, int out_size, void* d_ws, size_t ws_size,
                              hipStream_t stream) {
    const float* x     = (const float*)d_in[0];
    const float* qp    = (const float*)d_in[1];
    const float* W1    = (const float*)d_in[2];
    const float* b1    = (const float*)d_in[3];
    const float* W2    = (const float*)d_in[4];
    const float* b2    = (const float*)d_in[5];
    const float* gamma = (const float*)d_in[6];
    const float* beta  = (const float*)d_in[7];
    float* out = (float*)d_out;

    const int B = in_sizes[0] / 1296;           // 65536
    float* acc    = (float*)d_ws;               // 8 floats: sum[4], sumsq[4]
    float* logits = (float*)d_ws + 64;          // B*4 floats, 256B offset keeps float4 alignment

    const int nb = (B + 255) / 256;
    hipLaunchKernelGGL(k_init, dim3(1), dim3(64), 0, stream, acc);
    hipLaunchKernelGGL(k_main, dim3(nb), dim3(256), 0, stream,
                       x, qp, W1, b1, W2, b2, logits, acc, B);
    hipLaunchKernelGGL(k_norm, dim3(nb), dim3(256), 0, stream,
                       logits, acc, gamma, beta, out, B, 1.0f / (float)B);
}